// Round 4
// baseline (10090.025 us; speedup 1.0000x reference)
//
#include <hip/hip_runtime.h>
#include <cstdint>

#define NCLS 60
#define KC 512
#define DD 256
#define BB 32
#define NP 4096
#define DPAD 68   // padded LDS row stride (floats), multiple of 4 for b128 alignment
#define LDP 260   // row stride for the sq kernels

// Rounded fp32 multiply that cannot be fused into a following add. Non-volatile:
// the empty asm is an opaque value barrier (blocks fma contraction) but leaves
// the scheduler free to reorder independent chains.
__device__ __forceinline__ float mul_rn_nofuse(float a, float b) {
  float p = a * b;
  asm("" : "+v"(p));
  return p;
}

// numpy pairwise_sum of x*x over 256 contiguous floats:
// two 128-blocks (8-accumulator unroll each), halves added last.
__device__ __forceinline__ float np_pairwise256_sq(const float* row) {
  float h0 = 0.f, h1 = 0.f;
#pragma unroll
  for (int half = 0; half < 2; ++half) {
    const float* a = row + half * 128;
    float r[8];
#pragma unroll
    for (int j = 0; j < 8; ++j) r[j] = mul_rn_nofuse(a[j], a[j]);
    for (int blk = 1; blk < 16; ++blk) {
#pragma unroll
      for (int j = 0; j < 8; ++j) {
        float p = mul_rn_nofuse(a[blk * 8 + j], a[blk * 8 + j]);
        r[j] = r[j] + p;
      }
    }
    float res = ((r[0] + r[1]) + (r[2] + r[3])) + ((r[4] + r[5]) + (r[6] + r[7]));
    if (half == 0) h0 = res; else h1 = res;
  }
  return h0 + h1;
}

// ---- z_sq[b,n] = np.sum(z*z, -1) in numpy order (z_np[b,n,d] = z[b,d,n]) ----
__global__ __launch_bounds__(64) void zsq_kernel(const float* __restrict__ z,
                                                 float* __restrict__ zsq) {
  __shared__ float zs[64][LDP];
  int t = threadIdx.x;
  int b = blockIdx.x >> 6;
  int n0 = (blockIdx.x & 63) * 64;
  const float* zb = z + (size_t)b * DD * NP;
  for (int d = 0; d < DD; ++d) zs[t][d] = zb[(size_t)d * NP + n0 + t];
  __syncthreads();
  zsq[b * NP + n0 + t] = np_pairwise256_sq(&zs[t][0]);
}

// ---- cb_sq[row] = np.sum(emb*emb, -1) for all 60*512 rows ----
__global__ __launch_bounds__(64) void cbsq_kernel(const float* __restrict__ emb,
                                                  float* __restrict__ cbsq) {
  __shared__ float cs[64][LDP];
  int t = threadIdx.x;
  int r0 = blockIdx.x * 64;
  const float4* e4 = (const float4*)emb;
  for (int rr = 0; rr < 64; ++rr) {
    float4 v = e4[(size_t)(r0 + rr) * 64 + t];
    *(float4*)&cs[rr][t * 4] = v;
  }
  __syncthreads();
  cbsq[r0 + t] = np_pairwise256_sq(&cs[t][0]);
}

// ---- main: 8x4 micro-tile, np-einsum SSE chain order, fp32 dist, argmin ----
// block: 256 threads (tn = t>>4, tk = t&15); tile = 128 n x 64 k per kt.
// Thread owns n-rows {tn+16i, i<8}, k-rows {tk+16j, j<4}. Chain order per
// (n,k): d in 16-chunks ascending, reversed 4-sub-blocks, 4 lane-accs, hadd.
__global__ __launch_bounds__(256, 2) void vq_main_kernel(
    const float* __restrict__ z, const int* __restrict__ c,
    const float* __restrict__ emb, const float* __restrict__ zsq,
    const float* __restrict__ cbsq, int* __restrict__ idx_out) {
  __shared__ __align__(16) float zs[128][DPAD];
  __shared__ __align__(16) float cs[64][DPAD];
  const int t = threadIdx.x;
  const int b = blockIdx.y;
  const int n0 = blockIdx.x * 128;
  const int tn = t >> 4, tk = t & 15;
  const int cls = c[b];
  const float* __restrict__ zb = z + (size_t)b * DD * NP;
  const float* __restrict__ cb = emb + (size_t)cls * KC * DD;
  const float* __restrict__ cbsqb = cbsq + cls * KC;

  float zsqv[8];
#pragma unroll
  for (int i = 0; i < 8; ++i) zsqv[i] = zsq[b * NP + n0 + tn + 16 * i];

  float m[8];
  int bi[8];
#pragma unroll
  for (int i = 0; i < 8; ++i) { m[i] = 3.4e38f; bi[i] = 0; }

  for (int kt = 0; kt < 8; ++kt) {
    const float* __restrict__ cbk = cb + (size_t)kt * 64 * DD;
    float A[8][4][4];
#pragma unroll
    for (int i = 0; i < 8; ++i)
#pragma unroll
      for (int j = 0; j < 4; ++j)
#pragma unroll
        for (int l = 0; l < 4; ++l) A[i][j][l] = 0.f;

    for (int dc = 0; dc < 4; ++dc) {
      const int d0g = dc * 64;
      __syncthreads();  // previous chunk fully consumed
      // stage z chunk: 128 n x 64 d (coalesced over n; scalar LDS writes)
#pragma unroll
      for (int it = 0; it < 32; ++it) {
        int idx = it * 256 + t;
        int d = idx >> 7, n = idx & 127;
        zs[n][d] = zb[(size_t)(d0g + d) * NP + n0 + n];
      }
      // stage cb chunk: 64 k x 64 d (float4 both sides)
#pragma unroll
      for (int it = 0; it < 4; ++it) {
        int idx = it * 256 + t;
        int kr = idx >> 4, dq = idx & 15;
        *(float4*)&cs[kr][dq * 4] =
            *(const float4*)&cbk[(size_t)kr * DD + d0g + dq * 4];
      }
      __syncthreads();

#pragma unroll 1   // keep code size in I-cache; s-loop below fully unrolled
      for (int t16 = 0; t16 < 4; ++t16) {
#pragma unroll
        for (int s = 3; s >= 0; --s) {
          const int d0 = t16 * 16 + s * 4;
          float4 cf[4];
#pragma unroll
          for (int j = 0; j < 4; ++j) cf[j] = *(const float4*)&cs[tk + 16 * j][d0];
#pragma unroll
          for (int g = 0; g < 2; ++g) {
            float4 zf[4];
#pragma unroll
            for (int ii = 0; ii < 4; ++ii)
              zf[ii] = *(const float4*)&zs[tn + 16 * (g * 4 + ii)][d0];
#pragma unroll
            for (int ii = 0; ii < 4; ++ii) {
              const int i = g * 4 + ii;
              const float zz[4] = {zf[ii].x, zf[ii].y, zf[ii].z, zf[ii].w};
#pragma unroll
              for (int j = 0; j < 4; ++j) {
                const float cc[4] = {cf[j].x, cf[j].y, cf[j].z, cf[j].w};
#pragma unroll
                for (int l = 0; l < 4; ++l) {
                  float p = mul_rn_nofuse(zz[l], cc[l]);
                  A[i][j][l] = p + A[i][j][l];
                }
              }
            }
          }
        }
      }
    }

    // npyv hadd + dist + first-min update (k strictly ascending per thread)
#pragma unroll
    for (int j = 0; j < 4; ++j) {
      const int k = kt * 64 + tk + 16 * j;
      const float cq = cbsqb[k];
#pragma unroll
      for (int i = 0; i < 8; ++i) {
        float dot = (A[i][j][0] + A[i][j][1]) + (A[i][j][2] + A[i][j][3]);
        float dist = (zsqv[i] - 2.0f * dot) + cq;  // 2*dot exact (pow2 mul)
        if (dist < m[i]) { m[i] = dist; bi[i] = k; }
      }
    }
  }

  // lex-min (value, index) across the 16 tk-lanes sharing each n
#pragma unroll
  for (int i = 0; i < 8; ++i) {
#pragma unroll
    for (int off = 8; off >= 1; off >>= 1) {
      float om = __shfl_xor(m[i], off);
      int oi = __shfl_xor(bi[i], off);
      if (om < m[i] || (om == m[i] && oi < bi[i])) { m[i] = om; bi[i] = oi; }
    }
  }
  if (tk == 0) {
#pragma unroll
    for (int i = 0; i < 8; ++i) idx_out[b * NP + n0 + tn + 16 * i] = bi[i];
  }
}

// ---- gather selected rows -> [B,H,W,D] (bitwise copy of embedding rows) ----
__global__ __launch_bounds__(256) void vq_gather_kernel(
    const int* __restrict__ c, const float* __restrict__ emb,
    const int* __restrict__ idx, float* __restrict__ out) {
  int t = threadIdx.x;
  int r = blockIdx.x * 4 + (t >> 6);
  int lane = t & 63;
  int b = r >> 12;
  int k = idx[r];
  const float4* src = (const float4*)(emb + (size_t)(c[b] * KC + k) * DD);
  float4* dst = (float4*)(out + (size_t)r * DD);
  dst[lane] = src[lane];
}

extern "C" void kernel_launch(void* const* d_in, const int* in_sizes, int n_in,
                              void* d_out, int out_size, void* d_ws, size_t ws_size,
                              hipStream_t stream) {
  const float* z = (const float*)d_in[0];    // [32,256,64,64]
  const int* c = (const int*)d_in[1];        // [32]
  const float* emb = (const float*)d_in[2];  // [30720,256]
  float* out = (float*)d_out;                // [32,64,64,256]

  char* ws = (char*)d_ws;
  float* zsq = (float*)ws;                       // 131072 f32
  float* cbsq = (float*)(ws + 524288);           // 30720 f32
  int* idx = (int*)(ws + 524288 + 122880);       // 131072 i32

  zsq_kernel<<<BB * (NP / 64), 64, 0, stream>>>(z, zsq);
  cbsq_kernel<<<(NCLS * KC) / 64, 64, 0, stream>>>(emb, cbsq);
  dim3 gA(NP / 128, BB);
  vq_main_kernel<<<gA, 256, 0, stream>>>(z, c, emb, zsq, cbsq, idx);
  vq_gather_kernel<<<(BB * NP) / 4, 256, 0, stream>>>(c, emb, idx, out);
}

// Round 5
// 820.379 us; speedup vs baseline: 12.2992x; 12.2992x over previous
//
#include <hip/hip_runtime.h>
#include <cstdint>

#define NCLS 60
#define KC 512
#define DD 256
#define BB 32
#define NP 4096
#define DPAD 68   // padded LDS row stride (floats), multiple of 4 for b128 alignment
#define LDP 260   // row stride for the sq kernels

typedef float v2f __attribute__((ext_vector_type(2)));

// Packed fp32 mul/add: lo/hi lanes are IEEE RN f32, bit-identical to scalar
// v_mul_f32/v_add_f32. asm is opaque to the compiler -> no fma contraction.
__device__ __forceinline__ v2f pk_mul(v2f a, v2f b) {
  v2f d;
  asm("v_pk_mul_f32 %0, %1, %2" : "=v"(d) : "v"(a), "v"(b));
  return d;
}
__device__ __forceinline__ v2f pk_add(v2f a, v2f b) {
  v2f d;
  asm("v_pk_add_f32 %0, %1, %2" : "=v"(d) : "v"(a), "v"(b));
  return d;
}

// Rounded fp32 multiply that cannot be fused into a following add.
__device__ __forceinline__ float mul_rn_nofuse(float a, float b) {
  float p = a * b;
  asm("" : "+v"(p));
  return p;
}

// numpy pairwise_sum of x*x over 256 contiguous floats:
// two 128-blocks (8-accumulator unroll each), halves added last.
__device__ __forceinline__ float np_pairwise256_sq(const float* row) {
  float h0 = 0.f, h1 = 0.f;
#pragma unroll
  for (int half = 0; half < 2; ++half) {
    const float* a = row + half * 128;
    float r[8];
#pragma unroll
    for (int j = 0; j < 8; ++j) r[j] = mul_rn_nofuse(a[j], a[j]);
    for (int blk = 1; blk < 16; ++blk) {
#pragma unroll
      for (int j = 0; j < 8; ++j) {
        float p = mul_rn_nofuse(a[blk * 8 + j], a[blk * 8 + j]);
        r[j] = r[j] + p;
      }
    }
    float res = ((r[0] + r[1]) + (r[2] + r[3])) + ((r[4] + r[5]) + (r[6] + r[7]));
    if (half == 0) h0 = res; else h1 = res;
  }
  return h0 + h1;
}

// ---- z_sq[b,n] = np.sum(z*z, -1) in numpy order (z_np[b,n,d] = z[b,d,n]) ----
__global__ __launch_bounds__(64) void zsq_kernel(const float* __restrict__ z,
                                                 float* __restrict__ zsq) {
  __shared__ float zs[64][LDP];
  int t = threadIdx.x;
  int b = blockIdx.x >> 6;
  int n0 = (blockIdx.x & 63) * 64;
  const float* zb = z + (size_t)b * DD * NP;
  for (int d = 0; d < DD; ++d) zs[t][d] = zb[(size_t)d * NP + n0 + t];
  __syncthreads();
  zsq[b * NP + n0 + t] = np_pairwise256_sq(&zs[t][0]);
}

// ---- cb_sq[row] = np.sum(emb*emb, -1) for all 60*512 rows ----
__global__ __launch_bounds__(64) void cbsq_kernel(const float* __restrict__ emb,
                                                  float* __restrict__ cbsq) {
  __shared__ float cs[64][LDP];
  int t = threadIdx.x;
  int r0 = blockIdx.x * 64;
  const float4* e4 = (const float4*)emb;
  for (int rr = 0; rr < 64; ++rr) {
    float4 v = e4[(size_t)(r0 + rr) * 64 + t];
    *(float4*)&cs[rr][t * 4] = v;
  }
  __syncthreads();
  cbsq[r0 + t] = np_pairwise256_sq(&cs[t][0]);
}

// ---- main: 4x4 micro-tile, packed-fp32, np-einsum SSE chain order ----
// block: 256 threads (tn=t>>4, tk=t&15); tile = 64 n x 64 k per kt step.
// Thread owns n-rows {tn+16i, i<4}, k-rows {tk+16j, j<4}. Per (n,k) the chain
// is numpy's: d in 16-chunks ascending, reversed 4-sub-blocks, 4 lane-accs
// (2 VGPR pairs), hadd (a0+a1)+(a2+a3). All products/adds via v_pk_*_f32.
__global__ __launch_bounds__(256, 2) void vq_main_kernel(
    const float* __restrict__ z, const int* __restrict__ c,
    const float* __restrict__ emb, const float* __restrict__ zsq,
    const float* __restrict__ cbsq, int* __restrict__ idx_out) {
  __shared__ __align__(16) float zs[64][DPAD];
  __shared__ __align__(16) float cs[64][DPAD];
  const int t = threadIdx.x;
  const int b = blockIdx.y;
  const int n0 = blockIdx.x * 64;
  const int tn = t >> 4, tk = t & 15;
  const int cls = c[b];
  const float* __restrict__ zb = z + (size_t)b * DD * NP;
  const float* __restrict__ cb = emb + (size_t)cls * KC * DD;
  const float* __restrict__ cbsqb = cbsq + cls * KC;

  float zsqv[4];
#pragma unroll
  for (int i = 0; i < 4; ++i) zsqv[i] = zsq[b * NP + n0 + tn + 16 * i];

  float m[4];
  int bi[4];
#pragma unroll
  for (int i = 0; i < 4; ++i) { m[i] = 3.4e38f; bi[i] = 0; }

#pragma unroll 1
  for (int kt = 0; kt < 8; ++kt) {
    const float* __restrict__ cbk = cb + (size_t)kt * 64 * DD;
    v2f A[4][4][2];
#pragma unroll
    for (int i = 0; i < 4; ++i)
#pragma unroll
      for (int j = 0; j < 4; ++j)
#pragma unroll
        for (int p = 0; p < 2; ++p) A[i][j][p] = (v2f){0.f, 0.f};

#pragma unroll 1
    for (int dc = 0; dc < 4; ++dc) {
      const int d0g = dc * 64;
      __syncthreads();  // previous chunk fully consumed
      // stage z chunk: 64 n x 64 d (float4 global over n, scalar LDS scatter)
#pragma unroll
      for (int it = 0; it < 4; ++it) {
        int flat = it * 256 + t;
        int d = flat >> 4, n4 = flat & 15;
        float4 v = *(const float4*)&zb[(size_t)(d0g + d) * NP + n0 + n4 * 4];
        zs[n4 * 4 + 0][d] = v.x;
        zs[n4 * 4 + 1][d] = v.y;
        zs[n4 * 4 + 2][d] = v.z;
        zs[n4 * 4 + 3][d] = v.w;
      }
      // stage cb chunk: 64 k x 64 d (float4 both sides)
#pragma unroll
      for (int it = 0; it < 4; ++it) {
        int flat = it * 256 + t;
        int kr = flat >> 4, dq = flat & 15;
        *(float4*)&cs[kr][dq * 4] =
            *(const float4*)&cbk[(size_t)kr * DD + d0g + dq * 4];
      }
      __syncthreads();

#pragma unroll 1
      for (int t16 = 0; t16 < 4; ++t16) {
#pragma unroll
        for (int s = 3; s >= 0; --s) {
          const int d0 = t16 * 16 + s * 4;
          float4 cf[4], zf[4];
#pragma unroll
          for (int j = 0; j < 4; ++j) cf[j] = *(const float4*)&cs[tk + 16 * j][d0];
#pragma unroll
          for (int i = 0; i < 4; ++i) zf[i] = *(const float4*)&zs[tn + 16 * i][d0];
#pragma unroll
          for (int i = 0; i < 4; ++i) {
            const v2f zp0 = {zf[i].x, zf[i].y};
            const v2f zp1 = {zf[i].z, zf[i].w};
#pragma unroll
            for (int j = 0; j < 4; ++j) {
              const v2f cp0 = {cf[j].x, cf[j].y};
              const v2f cp1 = {cf[j].z, cf[j].w};
              A[i][j][0] = pk_add(pk_mul(zp0, cp0), A[i][j][0]);
              A[i][j][1] = pk_add(pk_mul(zp1, cp1), A[i][j][1]);
            }
          }
        }
      }
    }

    // npyv hadd + dist + first-min update (k strictly ascending per thread)
#pragma unroll
    for (int j = 0; j < 4; ++j) {
      const int k = kt * 64 + tk + 16 * j;
      const float cq = cbsqb[k];
#pragma unroll
      for (int i = 0; i < 4; ++i) {
        float dot = (A[i][j][0].x + A[i][j][0].y) + (A[i][j][1].x + A[i][j][1].y);
        float dist = (zsqv[i] - 2.0f * dot) + cq;  // 2*dot exact (pow2 mul)
        if (dist < m[i]) { m[i] = dist; bi[i] = k; }
      }
    }
  }

  // lex-min (value, index) across the 16 tk-lanes sharing each n
#pragma unroll
  for (int i = 0; i < 4; ++i) {
#pragma unroll
    for (int off = 8; off >= 1; off >>= 1) {
      float om = __shfl_xor(m[i], off);
      int oi = __shfl_xor(bi[i], off);
      if (om < m[i] || (om == m[i] && oi < bi[i])) { m[i] = om; bi[i] = oi; }
    }
  }
  if (tk == 0) {
#pragma unroll
    for (int i = 0; i < 4; ++i) idx_out[b * NP + n0 + tn + 16 * i] = bi[i];
  }
}

// ---- gather selected rows -> [B,H,W,D] (bitwise copy of embedding rows) ----
__global__ __launch_bounds__(256) void vq_gather_kernel(
    const int* __restrict__ c, const float* __restrict__ emb,
    const int* __restrict__ idx, float* __restrict__ out) {
  int t = threadIdx.x;
  int r = blockIdx.x * 4 + (t >> 6);
  int lane = t & 63;
  int b = r >> 12;
  int k = idx[r];
  const float4* src = (const float4*)(emb + (size_t)(c[b] * KC + k) * DD);
  float4* dst = (float4*)(out + (size_t)r * DD);
  dst[lane] = src[lane];
}

extern "C" void kernel_launch(void* const* d_in, const int* in_sizes, int n_in,
                              void* d_out, int out_size, void* d_ws, size_t ws_size,
                              hipStream_t stream) {
  const float* z = (const float*)d_in[0];    // [32,256,64,64]
  const int* c = (const int*)d_in[1];        // [32]
  const float* emb = (const float*)d_in[2];  // [30720,256]
  float* out = (float*)d_out;                // [32,64,64,256]

  char* ws = (char*)d_ws;
  float* zsq = (float*)ws;                       // 131072 f32
  float* cbsq = (float*)(ws + 524288);           // 30720 f32
  int* idx = (int*)(ws + 524288 + 122880);       // 131072 i32

  zsq_kernel<<<BB * (NP / 64), 64, 0, stream>>>(z, zsq);
  cbsq_kernel<<<(NCLS * KC) / 64, 64, 0, stream>>>(emb, cbsq);
  dim3 gA(NP / 64, BB);
  vq_main_kernel<<<gA, 256, 0, stream>>>(z, c, emb, zsq, cbsq, idx);
  vq_gather_kernel<<<(BB * NP) / 4, 256, 0, stream>>>(c, emb, idx, out);
}